// Round 14
// baseline (110.635 us; speedup 1.0000x reference)
//
#include <hip/hip_runtime.h>
#include <hip/hip_bf16.h>

// GatedMoE: B=8, T=4096, D=128, E=16, TOP_K=2 (f32 in/out, bf16 MFMA inside)
// out = concat(weighted_avg [NTOK*128] f32, consensus [NTOK] f32)
// R14 = R13 with nt-store types fixed (clang ext_vector f32x4, not HIP float4).
#define NTOK 32768
#define DD 128
#define NE 16
#define NGBLK 512    // gate blocks (64 tokens each)
#define NSEG 16      // segments per expert block
// ws layout (bytes); total 28 MiB
#define OFF_HDR    0                     // NE*NGBLK ints = 32 KiB
#define OFF_TOKW   (64*1024)             // NTOK*2 f32  = 256 KiB
#define OFF_LISTS  (512*1024)            // NE*NTOK int = 2 MiB
#define OFF_XB     (3*1024*1024)         // NTOK*128 bf16 = 8 MiB
#define OFF_EWT    (11*1024*1024)        // NE*128*128 bf16 = 512 KiB
#define OFF_YBUF   (12*1024*1024)        // NTOK*2*128 bf16 = 16 MiB

typedef __attribute__((ext_vector_type(8))) short bf16x8;
typedef __attribute__((ext_vector_type(8))) unsigned short u16x8;
typedef __attribute__((ext_vector_type(4))) float f32x4;

static __device__ inline ushort f2bf(float f) {      // RNE f32 -> bf16 bits
    uint u = __builtin_bit_cast(uint, f);
    u = u + 0x7FFFu + ((u >> 16) & 1u);
    return (ushort)(u >> 16);
}
static __device__ inline float b2f(ushort h) {
    uint u = ((uint)h) << 16;
    return __builtin_bit_cast(float, u);
}

// ---------------- Kernel 1: ewt (blocks 0-255) + gate (blocks 256-767) -------
// (validated R12)
__global__ __launch_bounds__(256) void prep_kernel(
    const float* __restrict__ x, const float* __restrict__ Wg,
    const float* __restrict__ bg, const float* __restrict__ Ew,
    ushort* __restrict__ ewT, int* __restrict__ hdr, int* __restrict__ lists,
    float* __restrict__ tokw, ushort* __restrict__ xb)
{
    __shared__ __align__(16) float smem[NE * DD + NE];   // gate WgT+Bg; ewt 32x33 tile
    __shared__ int sCnt[NE];
    const int bid = blockIdx.x, tid = threadIdx.x;

    if (bid < 256) {
        // ---- ewt half (validated) ----
        float (*tile)[33] = (float(*)[33])smem;
        const int e = bid >> 4, ki = ((bid >> 2) & 3) * 32, oi = (bid & 3) * 32;
        const int r = tid >> 3, c4 = (tid & 7) * 4;
        const float4 v = *(const float4*)(Ew + (size_t)e * DD * DD + (ki + r) * DD + oi + c4);
        tile[r][c4 + 0] = v.x; tile[r][c4 + 1] = v.y;
        tile[r][c4 + 2] = v.z; tile[r][c4 + 3] = v.w;
        __syncthreads();
        const int o = tid >> 3, k4 = (tid & 7) * 4;
        ushort4 s;
        s.x = f2bf(tile[k4 + 0][o]);
        s.y = f2bf(tile[k4 + 1][o]);
        s.z = f2bf(tile[k4 + 2][o]);
        s.w = f2bf(tile[k4 + 3][o]);
        *(ushort4*)(ewT + (size_t)e * DD * DD + (oi + o) * DD + ki + k4) = s;
        return;
    }

    // ---- gate half (validated R8 math; segment list build) ----
    const int gbid = bid - 256;
    float (*sWgT)[DD] = (float(*)[DD])smem;
    float* sBg = smem + NE * DD;
    for (int i = tid; i < DD * NE; i += 256) {
        int d = i & 127, e = i >> 7;
        sWgT[e][d] = Wg[d * NE + e];
    }
    if (tid < NE) { sBg[tid] = bg[tid]; sCnt[tid] = 0; }
    __syncthreads();

    const int t = gbid * 64 + (tid >> 2);
    const int g = tid & 3;
    const float* xt = x + (size_t)t * DD;
    ushort*      xo = xb + (size_t)t * DD;

    float logits[NE];
    #pragma unroll
    for (int e = 0; e < NE; ++e) logits[e] = 0.0f;

    #pragma unroll
    for (int i = 0; i < 8; ++i) {
        const int d0 = g * 4 + i * 16;
        float4 v = ((const float4*)xt)[g + i * 4];
        #pragma unroll
        for (int e = 0; e < NE; ++e) {
            float4 w4 = *(const float4*)&sWgT[e][d0];
            float a = logits[e];
            a = fmaf(v.x, w4.x, a);
            a = fmaf(v.y, w4.y, a);
            a = fmaf(v.z, w4.z, a);
            a = fmaf(v.w, w4.w, a);
            logits[e] = a;
        }
        ushort4 s; s.x = f2bf(v.x); s.y = f2bf(v.y); s.z = f2bf(v.z); s.w = f2bf(v.w);
        *(ushort4*)(xo + d0) = s;
    }

    #pragma unroll
    for (int e = 0; e < NE; ++e) {
        float a = logits[e];
        a += __shfl_xor(a, 1);
        a += __shfl_xor(a, 2);
        logits[e] = a + sBg[e];
    }

    float m = logits[0];
    #pragma unroll
    for (int e = 1; e < NE; ++e) m = fmaxf(m, logits[e]);
    float Z = 0.0f;
    #pragma unroll
    for (int e = 0; e < NE; ++e) Z += expf(logits[e] - m);

    int i1 = 0; float l1 = logits[0];
    #pragma unroll
    for (int e = 1; e < NE; ++e) if (logits[e] > l1) { l1 = logits[e]; i1 = e; }
    int i2 = -1; float l2 = -3.4e38f;
    #pragma unroll
    for (int e = 0; e < NE; ++e) if (e != i1 && logits[e] > l2) { l2 = logits[e]; i2 = e; }

    if (g == 0) {
        float p1 = expf(l1 - m) / Z;
        float p2 = expf(l2 - m) / Z;
        float s  = p1 + p2 + 1e-6f;
        tokw[t * 2 + 0] = p1 / s;
        tokw[t * 2 + 1] = p2 / s;
        int s1 = atomicAdd(&sCnt[i1], 1);
        int s2 = atomicAdd(&sCnt[i2], 1);
        lists[i1 * NTOK + gbid * 64 + s1] = t * 2 + 0;
        lists[i2 * NTOK + gbid * 64 + s2] = t * 2 + 1;
    }
    __syncthreads();
    if (tid < NE) hdr[tid * NGBLK + gbid] = sCnt[tid];
}

// ---------------- Kernel 2: grouped expert GEMM via bf16 MFMA ----------------
// (validated R12) grid (32, NE); block compacts 16 segments into LDS, then
// runs the validated MFMA tile body per 64-entry tile.
__global__ __launch_bounds__(256) void expert_kernel(
    const ushort* __restrict__ xb, const ushort* __restrict__ ewT,
    const int* __restrict__ hdr, const int* __restrict__ lists,
    ushort* __restrict__ ybuf)
{
    const int e = blockIdx.y;
    const int sg = blockIdx.x;           // segment group: segments sg*16..+15
    __shared__ int sCnt16[NSEG];
    __shared__ int sEnt[NSEG * 64];      // capacity exact: 16 segs x <=64
    const int tid = threadIdx.x;

    if (tid < NSEG) sCnt16[tid] = hdr[e * NGBLK + sg * NSEG + tid];
    __syncthreads();

    int off[NSEG + 1];
    off[0] = 0;
    #pragma unroll
    for (int s = 0; s < NSEG; ++s) off[s + 1] = off[s] + sCnt16[s];
    const int C = off[NSEG];
    if (C == 0) return;

    #pragma unroll
    for (int s = 0; s < NSEG; ++s) {
        const int c = sCnt16[s];
        const int* src = lists + e * NTOK + (sg * NSEG + s) * 64;
        for (int i = tid; i < c; i += 256) sEnt[off[s] + i] = src[i];
    }
    __syncthreads();

    const int lane = tid & 63, wv = tid >> 6;
    const int row  = lane & 15;          // token within wave tile == D column
    const int kg   = lane >> 4;          // k-group 0..3
    const ushort* ewe = ewT + (size_t)e * DD * DD;

    for (int base = 0; base < C; base += 64) {
        const int idx = base + wv * 16 + row;
        const int en  = (idx < C) ? sEnt[idx] : -1;
        const ushort* xrow = xb + (size_t)((en < 0 ? 0 : en) >> 1) * DD;

        bf16x8 xf[4];
        #pragma unroll
        for (int k = 0; k < 4; ++k)
            xf[k] = *(const bf16x8*)(xrow + k * 32 + kg * 8);

        f32x4 acc[8];
        #pragma unroll
        for (int n = 0; n < 8; ++n) acc[n] = (f32x4)(0.0f);

        #pragma unroll
        for (int n = 0; n < 8; ++n) {
            const ushort* er = ewe + (size_t)(n * 16 + row) * DD + kg * 8;
            #pragma unroll
            for (int k = 0; k < 4; ++k) {
                bf16x8 ef = *(const bf16x8*)(er + k * 32);
                acc[n] = __builtin_amdgcn_mfma_f32_16x16x32_bf16(ef, xf[k], acc[n], 0, 0, 0);
            }
        }

        if (en >= 0) {
            ushort* yr = ybuf + (size_t)en * DD + kg * 4;   // o = n*16+kg*4+reg
            #pragma unroll
            for (int n = 0; n < 8; ++n) {
                ushort4 s;
                s.x = f2bf(acc[n][0]); s.y = f2bf(acc[n][1]);
                s.z = f2bf(acc[n][2]); s.w = f2bf(acc[n][3]);
                *(ushort4*)(yr + n * 16) = s;
            }
        }
    }
}

// ---------------- Kernel 3: combine (avg, var, consensus) -------------------
// R14: 16B ybuf loads (ushort8/lane), wave = 2 tokens/pass x 8 passes.
// lane = half*32 + tp*16 + dg: half = slot, tp = token-of-pair, dg = dim/8.
// shfl_xor(32) exchanges slots; nt stores (f32x4 ext_vector) for avg/cons.
__global__ __launch_bounds__(256) void combine_kernel(
    const ushort* __restrict__ ybuf, const float* __restrict__ tokw,
    float* __restrict__ avg_out, float* __restrict__ cons_out)
{
    const int tid = threadIdx.x;
    const int lane = tid & 63, wv = tid >> 6;
    const int half = lane >> 5;          // slot 0/1
    const int hl = lane & 31;
    const int tp = hl >> 4, dg = hl & 15;
    const int t0 = blockIdx.x * 64 + wv * 16;

    #pragma unroll
    for (int j = 0; j < 8; ++j) {
        const int t = t0 + j * 2 + tp;
        const float2 w = *(const float2*)(tokw + (size_t)t * 2);
        const float wo = half ? w.y : w.x;
        const float wx = half ? w.x : w.y;

        u16x8 raw = *(const u16x8*)(ybuf + (size_t)(t * 2 + half) * DD + dg * 8);
        float o[8], q[8], a[8];
        #pragma unroll
        for (int i = 0; i < 8; ++i) o[i] = b2f(raw[i]);
        #pragma unroll
        for (int i = 0; i < 8; ++i) q[i] = __shfl_xor(o[i], 32);

        float v = 0.0f;
        #pragma unroll
        for (int i = 0; i < 8; ++i) {
            a[i] = wo * o[i] + wx * q[i];
            float d = o[i] - a[i], ee = q[i] - a[i];
            v = fmaf(wo, d * d, fmaf(wx, ee * ee, v));
        }
        if (half == 0) {
            f32x4* dst = (f32x4*)(avg_out + (size_t)t * DD + dg * 8);
            f32x4 lo; lo[0] = a[0]; lo[1] = a[1]; lo[2] = a[2]; lo[3] = a[3];
            f32x4 hi; hi[0] = a[4]; hi[1] = a[5]; hi[2] = a[6]; hi[3] = a[7];
            __builtin_nontemporal_store(lo, dst);
            __builtin_nontemporal_store(hi, dst + 1);
        }
        // reduce v over the 16 dg-lanes (lane bits 0..3)
        v += __shfl_xor(v, 1);
        v += __shfl_xor(v, 2);
        v += __shfl_xor(v, 4);
        v += __shfl_xor(v, 8);
        if (half == 0 && dg == 0)
            __builtin_nontemporal_store(expf(-v * (1.0f / 128.0f)), cons_out + t);
    }
}

// ---------------- launcher ---------------------------------------------------
extern "C" void kernel_launch(void* const* d_in, const int* in_sizes, int n_in,
                              void* d_out, int out_size, void* d_ws, size_t ws_size,
                              hipStream_t stream)
{
    const float* x  = (const float*)d_in[0];
    const float* Wg = (const float*)d_in[1];
    const float* bg = (const float*)d_in[2];
    const float* Ew = (const float*)d_in[3];
    float* out = (float*)d_out;

    char* ws = (char*)d_ws;
    int*    hdr   = (int*)(ws + OFF_HDR);
    float*  tokw  = (float*)(ws + OFF_TOKW);
    int*    lists = (int*)(ws + OFF_LISTS);
    ushort* xbuf  = (ushort*)(ws + OFF_XB);
    ushort* ewT   = (ushort*)(ws + OFF_EWT);
    ushort* ybuf  = (ushort*)(ws + OFF_YBUF);

    prep_kernel<<<256 + NGBLK, 256, 0, stream>>>(x, Wg, bg, Ew, ewT, hdr, lists, tokw, xbuf);
    expert_kernel<<<dim3(NGBLK / NSEG, NE), 256, 0, stream>>>(xbuf, ewT, hdr, lists, ybuf);
    combine_kernel<<<NTOK / 64, 256, 0, stream>>>(ybuf, tokw, out, out + (size_t)NTOK * DD);
}